// Round 1
// baseline (116.515 us; speedup 1.0000x reference)
//
#include <hip/hip_runtime.h>

#define B_ 32
#define P_ 16384
#define N_ 64
#define S_ 5

constexpr int CHUNKS_A = 32;
constexpr int PRED_PER_BLK_A = P_ / CHUNKS_A;   // 512
constexpr int CHUNKS_C = 8;
constexpr int PRED_PER_BLK_C = P_ / CHUNKS_C;   // 2048

// acc layout per batch (stride 12 floats):
// 0 box_l, 1 scale_l, 2 ctx_l, 3 nv, 4 conf_corr (=-sum score*iou over winners),
// 5 softplus(pscore) sum, 6 box_reg sum, 7 scale_reg sum, 8 ctx_reg sum
constexpr int ACC_STRIDE = 12;

__device__ __forceinline__ float softplusf_(float x) {
  return fmaxf(x, 0.f) + log1pf(__expf(-fabsf(x)));
}

// ---------------- kA: per-target best IoU + argmax over all preds ----------------
__global__ __launch_bounds__(256) void kA(const float4* __restrict__ pbox,
                                          const float4* __restrict__ tbox,
                                          unsigned long long* __restrict__ best) {
  __shared__ float sx1[PRED_PER_BLK_A], sy1[PRED_PER_BLK_A],
                   sx2[PRED_PER_BLK_A], sy2[PRED_PER_BLK_A], sar[PRED_PER_BLK_A];
  __shared__ float tg[5][N_];
  const int b = blockIdx.x / CHUNKS_A;
  const int chunk = blockIdx.x % CHUNKS_A;
  const int tid = threadIdx.x;

  if (tid < N_) {
    float4 t = tbox[b * N_ + tid];
    tg[0][tid] = t.x; tg[1][tid] = t.y; tg[2][tid] = t.z; tg[3][tid] = t.w;
    tg[4][tid] = (t.z - t.x) * (t.w - t.y);
  }
  const int base = chunk * PRED_PER_BLK_A;
  for (int i = tid; i < PRED_PER_BLK_A; i += 256) {
    float4 pb = pbox[b * P_ + base + i];
    sx1[i] = pb.x; sy1[i] = pb.y; sx2[i] = pb.z; sy2[i] = pb.w;
    sar[i] = (pb.z - pb.x) * (pb.w - pb.y);
  }
  __syncthreads();

  const int n = tid & 63;          // target (lanes of a wave = 64 targets -> LDS broadcast)
  const int g = tid >> 6;          // pred sub-group (4 groups)
  const float gx1 = tg[0][n], gy1 = tg[1][n], gx2 = tg[2][n], gy2 = tg[3][n], gar = tg[4][n];

  float bi = -1.f; int bidx = 0;
  const int j0 = g * (PRED_PER_BLK_A / 4);   // 128 preds per thread, ascending idx
  #pragma unroll 4
  for (int j = j0; j < j0 + PRED_PER_BLK_A / 4; ++j) {
    float lx = fmaxf(sx1[j], gx1), ly = fmaxf(sy1[j], gy1);
    float rx = fminf(sx2[j], gx2), ry = fminf(sy2[j], gy2);
    float w = fmaxf(rx - lx, 0.f), h = fmaxf(ry - ly, 0.f);
    float inter = w * h;
    float uni = sar[j] + gar - inter;
    float iou = inter * __builtin_amdgcn_rcpf(uni);
    bool upd = iou > bi;           // strict > keeps first (lowest) index within thread
    bi   = upd ? iou : bi;
    bidx = upd ? base + j : bidx;
  }
  // pack so atomicMax picks max iou, and on exact iou tie the SMALLEST idx (JAX argmax)
  unsigned long long packed =
      ((unsigned long long)__float_as_uint(bi) << 32) |
      (unsigned long long)(0xFFFFFFFFu - (unsigned)bidx);
  atomicMax(&best[b * N_ + n], packed);
}

// ---------------- kB: per-target losses + conf correction (one wave per batch) ----
__global__ __launch_bounds__(64) void kB(const unsigned long long* __restrict__ best,
                                         const float* __restrict__ pscore,
                                         const float4* __restrict__ pbox,
                                         const float* __restrict__ pscale,
                                         const float* __restrict__ pctx,
                                         const float4* __restrict__ tbox,
                                         const int* __restrict__ tscale,
                                         const float* __restrict__ tctx,
                                         float* __restrict__ acc) {
  const int b = blockIdx.x, n = threadIdx.x;
  __shared__ float s_iou[N_];
  __shared__ unsigned s_idx[N_];

  unsigned long long pk = best[b * N_ + n];
  float iou = __uint_as_float((unsigned)(pk >> 32));
  unsigned idx = 0xFFFFFFFFu - (unsigned)(pk & 0xFFFFFFFFull);
  bool valid = iou > 0.5f;
  s_iou[n] = iou;
  s_idx[n] = valid ? idx : 0xFFFFFFFFu;
  __syncthreads();

  float boxv = 0.f, scalev = 0.f, ctxv = 0.f, corrv = 0.f;
  float nvv = valid ? 1.f : 0.f;
  if (valid) {
    float4 pb = pbox[b * P_ + idx];
    float4 tb = tbox[b * N_ + n];
    float s1 = 0.f;
    { float d = fabsf(pb.x - tb.x); s1 += (d < 0.1f) ? 5.f * d * d : d - 0.05f; }
    { float d = fabsf(pb.y - tb.y); s1 += (d < 0.1f) ? 5.f * d * d : d - 0.05f; }
    { float d = fabsf(pb.z - tb.z); s1 += (d < 0.1f) ? 5.f * d * d : d - 0.05f; }
    { float d = fabsf(pb.w - tb.w); s1 += (d < 0.1f) ? 5.f * d * d : d - 0.05f; }
    boxv = s1 * iou;

    const float* ps = pscale + (size_t)(b * P_ + idx) * S_;
    float x0 = ps[0], x1 = ps[1], x2 = ps[2], x3 = ps[3], x4 = ps[4];
    float m = fmaxf(fmaxf(fmaxf(x0, x1), fmaxf(x2, x3)), x4);
    float lse = m + logf(expf(x0 - m) + expf(x1 - m) + expf(x2 - m) +
                         expf(x3 - m) + expf(x4 - m));
    int tc = tscale[b * N_ + n];
    scalev = lse - ps[tc];

    float x = pctx[b * P_ + idx], y = tctx[b * N_ + n];
    ctxv = fmaxf(x, 0.f) - x * y + log1pf(expf(-fabsf(x)));

    // winner dedup for scatter-max conf_target: keep lane with max iou per idx,
    // tie -> lowest lane (matches .at[].max on identical values)
    bool winner = true;
    for (int m2 = 0; m2 < N_; ++m2) {
      if (m2 == n) continue;
      if (s_idx[m2] == idx) {
        float im = s_iou[m2];
        if (im > iou || (im == iou && m2 < n)) winner = false;
      }
    }
    if (winner) corrv = -pscore[b * P_ + idx] * iou;  // bce(x,t) - softplus(x) = -x*t
  }

  for (int o = 32; o; o >>= 1) {
    boxv  += __shfl_down(boxv, o);
    scalev += __shfl_down(scalev, o);
    ctxv  += __shfl_down(ctxv, o);
    corrv += __shfl_down(corrv, o);
    nvv   += __shfl_down(nvv, o);
  }
  if (n == 0) {
    float denom = fmaxf(nvv, 1.f);
    float* a = acc + b * ACC_STRIDE;
    a[0] = boxv / (denom * 4.f);
    a[1] = scalev / denom;
    a[2] = ctxv / denom;
    a[3] = nvv;
    a[4] = corrv;
  }
}

// ---------------- kC: softplus(pscore) sum; reg sums only if batch has no match ---
__global__ __launch_bounds__(256) void kC(const float4* __restrict__ pscore4,
                                          const float4* __restrict__ pbox,
                                          const float* __restrict__ pscale,
                                          const float4* __restrict__ pctx4,
                                          float* __restrict__ acc) {
  const int b = blockIdx.x / CHUNKS_C;
  const int chunk = blockIdx.x % CHUNKS_C;
  const int tid = threadIdx.x;
  const bool need_reg = !(acc[b * ACC_STRIDE + 3] > 0.f);  // block-uniform
  const int baseP = b * P_ + chunk * PRED_PER_BLK_C;

  float sps = 0.f, boxr = 0.f, scaler = 0.f, ctxr = 0.f;
  for (int i = tid; i < PRED_PER_BLK_C / 4; i += 256) {
    float4 v = pscore4[(baseP >> 2) + i];
    sps += softplusf_(v.x) + softplusf_(v.y) + softplusf_(v.z) + softplusf_(v.w);
  }
  if (need_reg) {
    for (int i = tid; i < PRED_PER_BLK_C; i += 256) {
      float4 t = pbox[baseP + i];
      boxr += fabsf(t.x) + fabsf(t.y) + fabsf(t.z) + fabsf(t.w);
    }
    const float* psc = pscale + (size_t)baseP * S_;
    for (int i = tid; i < PRED_PER_BLK_C * S_; i += 256) {
      float v = psc[i];
      float vp = v + 1e-6f;
      scaler -= v * logf(vp > 0.f ? vp : 1.f);
    }
    for (int i = tid; i < PRED_PER_BLK_C / 4; i += 256) {
      float4 v = pctx4[(baseP >> 2) + i];
      ctxr += softplusf_(v.x) + softplusf_(v.y) + softplusf_(v.z) + softplusf_(v.w);
    }
  }
  for (int o = 32; o; o >>= 1) {
    sps += __shfl_down(sps, o);
    if (need_reg) {
      boxr += __shfl_down(boxr, o);
      scaler += __shfl_down(scaler, o);
      ctxr += __shfl_down(ctxr, o);
    }
  }
  if ((tid & 63) == 0) {
    float* a = acc + b * ACC_STRIDE;
    atomicAdd(&a[5], sps);
    if (need_reg) {
      atomicAdd(&a[6], boxr);
      atomicAdd(&a[7], scaler);
      atomicAdd(&a[8], ctxr);
    }
  }
}

// ---------------- kD: batch mean + weights -> 5 outputs ---------------------------
__global__ __launch_bounds__(64) void kD(const float* __restrict__ acc,
                                         float* __restrict__ out) {
  const int t = threadIdx.x;
  float bl = 0.f, sl = 0.f, cl = 0.f, fl = 0.f;
  if (t < B_) {
    const float* a = acc + t * ACC_STRIDE;
    bool anyv = a[3] > 0.f;
    bl = anyv ? a[0] : 0.1f * (a[6] / (float)(P_ * 4));
    sl = anyv ? a[1] : 0.1f * (a[7] / (float)(P_ * S_));
    cl = anyv ? a[2] : 0.1f * (a[8] / (float)P_);
    fl = (a[5] + a[4]) / (float)P_;   // conf path is identical formula in both branches
  }
  for (int o = 32; o; o >>= 1) {
    bl += __shfl_down(bl, o);
    sl += __shfl_down(sl, o);
    cl += __shfl_down(cl, o);
    fl += __shfl_down(fl, o);
  }
  if (t == 0) {
    float box_loss   = 2.0f * (bl / (float)B_);
    float scale_loss = 1.0f * (sl / (float)B_);
    float ctx_loss   = 1.5f * (cl / (float)B_);
    float conf_loss  = 1.0f * (fl / (float)B_);
    out[0] = box_loss + scale_loss + ctx_loss + conf_loss;
    out[1] = box_loss;
    out[2] = scale_loss;
    out[3] = ctx_loss;
    out[4] = conf_loss;
  }
}

extern "C" void kernel_launch(void* const* d_in, const int* in_sizes, int n_in,
                              void* d_out, int out_size, void* d_ws, size_t ws_size,
                              hipStream_t stream) {
  const float*  pscore = (const float*)d_in[0];
  const float4* pbox   = (const float4*)d_in[1];
  const float*  pscale = (const float*)d_in[2];
  const float*  pctx   = (const float*)d_in[3];
  const float4* tbox   = (const float4*)d_in[4];
  const int*    tscale = (const int*)d_in[5];
  const float*  tctx   = (const float*)d_in[6];
  // d_in[7] target_conf: read but unused by reference

  unsigned long long* best = (unsigned long long*)d_ws;
  float* acc = (float*)((char*)d_ws + (size_t)B_ * N_ * sizeof(unsigned long long));
  size_t zero_bytes = (size_t)B_ * N_ * sizeof(unsigned long long) +
                      (size_t)B_ * ACC_STRIDE * sizeof(float);
  hipMemsetAsync(d_ws, 0, zero_bytes, stream);

  hipLaunchKernelGGL(kA, dim3(B_ * CHUNKS_A), dim3(256), 0, stream, pbox, tbox, best);
  hipLaunchKernelGGL(kB, dim3(B_), dim3(64), 0, stream, best, pscore, pbox, pscale,
                     pctx, tbox, tscale, tctx, acc);
  hipLaunchKernelGGL(kC, dim3(B_ * CHUNKS_C), dim3(256), 0, stream,
                     (const float4*)pscore, pbox, pscale, (const float4*)pctx, acc);
  hipLaunchKernelGGL(kD, dim3(1), dim3(64), 0, stream, acc, (float*)d_out);
}

// Round 3
// 116.461 us; speedup vs baseline: 1.0005x; 1.0005x over previous
//
#include <hip/hip_runtime.h>

#define B_ 32
#define P_ 16384
#define N_ 64
#define S_ 5

constexpr int CHUNKS = 64;                    // blocks per batch in kA
constexpr int PRED_PER_BLK = P_ / CHUNKS;     // 256 preds per block
constexpr int ACC_STRIDE = 12;

// acc layout per batch:
// 0 box_l, 1 scale_l, 2 ctx_l, 3 nv, 4 conf_corr,
// 5 softplus(pscore) sum, 6 box_reg sum, 7 scale_reg sum, 8 ctx_reg sum

__device__ __forceinline__ float softplusf_(float x) {
  return fmaxf(x, 0.f) + log1pf(__expf(-fabsf(x)));
}

// ---------------- kA: per-chunk best IoU+argmax candidates + partial sums ---------
// grid: B_*CHUNKS blocks of 256. Each block: 256 preds vs all 64 targets.
// Also computes (branchless) partial sums: softplus(pscore), |pbox|,
// -pscale*log(safe), softplus(pctx) for the fallback/conf paths.
__global__ __launch_bounds__(256) void kA(const float4* __restrict__ pbox,
                                          const float4* __restrict__ tbox,
                                          const float* __restrict__ pscore,
                                          const float* __restrict__ pscale,
                                          const float* __restrict__ pctx,
                                          unsigned long long* __restrict__ cand,
                                          float4* __restrict__ partial) {
  __shared__ float4 sbox[PRED_PER_BLK];
  __shared__ float  sar[PRED_PER_BLK];
  __shared__ float  tg[5][N_];
  __shared__ unsigned long long merge[4][N_];
  __shared__ float  red[4][4];

  const int b     = blockIdx.x / CHUNKS;
  const int chunk = blockIdx.x % CHUNKS;
  const int tid   = threadIdx.x;
  const int base  = chunk * PRED_PER_BLK;
  const int gbase = b * P_ + base;

  if (tid < N_) {
    float4 t = tbox[b * N_ + tid];
    tg[0][tid] = t.x; tg[1][tid] = t.y; tg[2][tid] = t.z; tg[3][tid] = t.w;
    tg[4][tid] = (t.z - t.x) * (t.w - t.y);
  }
  // stage this chunk's preds (1 float4 per thread) + reg partials
  float4 pb = pbox[gbase + tid];
  sbox[tid] = pb;
  sar[tid]  = (pb.z - pb.x) * (pb.w - pb.y);
  float boxr = fabsf(pb.x) + fabsf(pb.y) + fabsf(pb.z) + fabsf(pb.w);
  float sps  = softplusf_(pscore[gbase + tid]);
  float ctxr = softplusf_(pctx[gbase + tid]);
  float scaler = 0.f;
  const float* psc = pscale + (size_t)gbase * S_;
  #pragma unroll
  for (int i = 0; i < S_; ++i) {               // 1280 contiguous floats, coalesced
    float v  = psc[tid + i * 256];
    float vp = v + 1e-6f;
    scaler  -= v * logf(vp > 0.f ? vp : 1.f);
  }
  __syncthreads();

  const int n = tid & 63;                      // lane = target -> LDS broadcast reads
  const int g = tid >> 6;                      // wave = pred sub-range (ascending)
  const float gx1 = tg[0][n], gy1 = tg[1][n], gx2 = tg[2][n], gy2 = tg[3][n],
              gar = tg[4][n];

  float bi = -1.f; int bj = 0;
  const int j0 = g * (PRED_PER_BLK / 4);       // 64 preds per thread, ascending j
  #pragma unroll 4
  for (int j = j0; j < j0 + PRED_PER_BLK / 4; ++j) {
    float4 q  = sbox[j];                       // ds_read_b128, broadcast
    float su  = sar[j] + gar;                  // ds_read_b32
    float w   = fmaxf(fminf(q.z, gx2) - fmaxf(q.x, gx1), 0.f);
    float h   = fmaxf(fminf(q.w, gy2) - fmaxf(q.y, gy1), 0.f);
    float inter = w * h;
    float iou = inter * __builtin_amdgcn_rcpf(su - inter);
    bool upd  = iou > bi;                      // strict > keeps lowest j in range
    bi = upd ? iou : bi;
    bj = upd ? j : bj;
  }
  // pack: u64 max == (max iou, tie -> smallest global idx) — JAX argmax semantics
  merge[g][n] = ((unsigned long long)__float_as_uint(bi) << 32) |
                (unsigned long long)(0xFFFFFFFFu - (unsigned)(base + bj));

  // wave-reduce the 4 partial sums
  float p0 = sps, p1 = boxr, p2 = scaler, p3 = ctxr;
  for (int o = 32; o; o >>= 1) {
    p0 += __shfl_down(p0, o); p1 += __shfl_down(p1, o);
    p2 += __shfl_down(p2, o); p3 += __shfl_down(p3, o);
  }
  if (n == 0) { red[g][0] = p0; red[g][1] = p1; red[g][2] = p2; red[g][3] = p3; }
  __syncthreads();

  if (tid < N_) {                              // merge 4 wave-candidates per target
    unsigned long long m = merge[0][tid];
    unsigned long long v1 = merge[1][tid]; m = v1 > m ? v1 : m;
    unsigned long long v2 = merge[2][tid]; m = v2 > m ? v2 : m;
    unsigned long long v3 = merge[3][tid]; m = v3 > m ? v3 : m;
    cand[(size_t)blockIdx.x * N_ + tid] = m;   // coalesced 512B store
  }
  if (tid == 64) {
    partial[blockIdx.x] =
        make_float4(red[0][0] + red[1][0] + red[2][0] + red[3][0],
                    red[0][1] + red[1][1] + red[2][1] + red[3][1],
                    red[0][2] + red[1][2] + red[2][2] + red[3][2],
                    red[0][3] + red[1][3] + red[2][3] + red[3][3]);
  }
}

// ---------------- kB: merge candidates, per-target losses, partial-sum reduce -----
__global__ __launch_bounds__(64) void kB(const unsigned long long* __restrict__ cand,
                                         const float4* __restrict__ partial,
                                         const float* __restrict__ pscore,
                                         const float4* __restrict__ pbox,
                                         const float* __restrict__ pscale,
                                         const float* __restrict__ pctx,
                                         const float4* __restrict__ tbox,
                                         const int* __restrict__ tscale,
                                         const float* __restrict__ tctx,
                                         float* __restrict__ acc) {
  const int b = blockIdx.x, n = threadIdx.x;
  __shared__ float s_iou[N_];
  __shared__ unsigned s_idx[N_];

  // merge the CHUNKS candidates for target n (all iou>=0 so packed>0)
  unsigned long long pk = 0ull;
  const unsigned long long* cb = cand + (size_t)b * CHUNKS * N_ + n;
  #pragma unroll 8
  for (int c = 0; c < CHUNKS; ++c) {
    unsigned long long v = cb[(size_t)c * N_];
    pk = v > pk ? v : pk;
  }

  float iou = __uint_as_float((unsigned)(pk >> 32));
  unsigned idx = 0xFFFFFFFFu - (unsigned)(pk & 0xFFFFFFFFull);
  bool valid = iou > 0.5f;
  s_iou[n] = iou;
  s_idx[n] = valid ? idx : 0xFFFFFFFFu;
  __syncthreads();

  float boxv = 0.f, scalev = 0.f, ctxv = 0.f, corrv = 0.f;
  float nvv = valid ? 1.f : 0.f;
  if (valid) {
    float4 pb = pbox[b * P_ + idx];
    float4 tb = tbox[b * N_ + n];
    float s1 = 0.f;
    { float d = fabsf(pb.x - tb.x); s1 += (d < 0.1f) ? 5.f * d * d : d - 0.05f; }
    { float d = fabsf(pb.y - tb.y); s1 += (d < 0.1f) ? 5.f * d * d : d - 0.05f; }
    { float d = fabsf(pb.z - tb.z); s1 += (d < 0.1f) ? 5.f * d * d : d - 0.05f; }
    { float d = fabsf(pb.w - tb.w); s1 += (d < 0.1f) ? 5.f * d * d : d - 0.05f; }
    boxv = s1 * iou;

    const float* ps = pscale + (size_t)(b * P_ + idx) * S_;
    float x0 = ps[0], x1 = ps[1], x2 = ps[2], x3 = ps[3], x4 = ps[4];
    float m = fmaxf(fmaxf(fmaxf(x0, x1), fmaxf(x2, x3)), x4);
    float lse = m + logf(expf(x0 - m) + expf(x1 - m) + expf(x2 - m) +
                         expf(x3 - m) + expf(x4 - m));
    int tc = tscale[b * N_ + n];
    scalev = lse - ps[tc];

    float x = pctx[b * P_ + idx], y = tctx[b * N_ + n];
    ctxv = fmaxf(x, 0.f) - x * y + log1pf(expf(-fabsf(x)));

    // scatter-max dedup: one lane per matched pred contributes -score*max_iou
    bool winner = true;
    for (int m2 = 0; m2 < N_; ++m2) {
      if (m2 == n) continue;
      if (s_idx[m2] == idx) {
        float im = s_iou[m2];
        if (im > iou || (im == iou && m2 < n)) winner = false;
      }
    }
    if (winner) corrv = -pscore[b * P_ + idx] * iou;  // bce(x,t)-softplus(x) = -x*t
  }

  for (int o = 32; o; o >>= 1) {
    boxv  += __shfl_down(boxv, o);
    scalev += __shfl_down(scalev, o);
    ctxv  += __shfl_down(ctxv, o);
    corrv += __shfl_down(corrv, o);
    nvv   += __shfl_down(nvv, o);
  }

  // reduce the CHUNKS(=64) per-chunk partial float4s for this batch
  float4 pp = partial[b * CHUNKS + n];
  float sps = pp.x, boxr = pp.y, scaler = pp.z, ctxr = pp.w;
  for (int o = 32; o; o >>= 1) {
    sps += __shfl_down(sps, o);
    boxr += __shfl_down(boxr, o);
    scaler += __shfl_down(scaler, o);
    ctxr += __shfl_down(ctxr, o);
  }

  if (n == 0) {
    float denom = fmaxf(nvv, 1.f);
    float* a = acc + b * ACC_STRIDE;
    a[0] = boxv / (denom * 4.f);
    a[1] = scalev / denom;
    a[2] = ctxv / denom;
    a[3] = nvv;
    a[4] = corrv;
    a[5] = sps;
    a[6] = boxr;
    a[7] = scaler;
    a[8] = ctxr;
  }
}

// ---------------- kD: batch mean + weights -> 5 outputs ---------------------------
__global__ __launch_bounds__(64) void kD(const float* __restrict__ acc,
                                         float* __restrict__ out) {
  const int t = threadIdx.x;
  float bl = 0.f, sl = 0.f, cl = 0.f, fl = 0.f;
  if (t < B_) {
    const float* a = acc + t * ACC_STRIDE;
    bool anyv = a[3] > 0.f;
    bl = anyv ? a[0] : 0.1f * (a[6] / (float)(P_ * 4));
    sl = anyv ? a[1] : 0.1f * (a[7] / (float)(P_ * S_));
    cl = anyv ? a[2] : 0.1f * (a[8] / (float)P_);
    fl = (a[5] + a[4]) / (float)P_;   // conf formula identical in both branches
  }
  for (int o = 32; o; o >>= 1) {
    bl += __shfl_down(bl, o);
    sl += __shfl_down(sl, o);
    cl += __shfl_down(cl, o);
    fl += __shfl_down(fl, o);
  }
  if (t == 0) {
    float box_loss   = 2.0f * (bl / (float)B_);
    float scale_loss = 1.0f * (sl / (float)B_);
    float ctx_loss   = 1.5f * (cl / (float)B_);
    float conf_loss  = 1.0f * (fl / (float)B_);
    out[0] = box_loss + scale_loss + ctx_loss + conf_loss;
    out[1] = box_loss;
    out[2] = scale_loss;
    out[3] = ctx_loss;
    out[4] = conf_loss;
  }
}

extern "C" void kernel_launch(void* const* d_in, const int* in_sizes, int n_in,
                              void* d_out, int out_size, void* d_ws, size_t ws_size,
                              hipStream_t stream) {
  const float*  pscore = (const float*)d_in[0];
  const float4* pbox   = (const float4*)d_in[1];
  const float*  pscale = (const float*)d_in[2];
  const float*  pctx   = (const float*)d_in[3];
  const float4* tbox   = (const float4*)d_in[4];
  const int*    tscale = (const int*)d_in[5];
  const float*  tctx   = (const float*)d_in[6];
  // d_in[7] target_conf: read but unused by reference

  unsigned long long* cand = (unsigned long long*)d_ws;      // B*CHUNKS*N u64 = 1 MB
  float4* partial = (float4*)((char*)d_ws + (size_t)B_ * CHUNKS * N_ * 8);  // 32 KB
  float* acc = (float*)((char*)partial + (size_t)B_ * CHUNKS * sizeof(float4));

  hipLaunchKernelGGL(kA, dim3(B_ * CHUNKS), dim3(256), 0, stream,
                     pbox, tbox, pscore, pscale, pctx, cand, partial);
  hipLaunchKernelGGL(kB, dim3(B_), dim3(64), 0, stream, cand, partial, pscore,
                     pbox, pscale, pctx, tbox, tscale, tctx, acc);
  hipLaunchKernelGGL(kD, dim3(1), dim3(64), 0, stream, acc, (float*)d_out);
}